// Round 12
// baseline (11992.911 us; speedup 1.0000x reference)
//
#include <hip/hip_runtime.h>
#include <hip/hip_bf16.h>

typedef __hip_bfloat16 bf16;

#define BB 32
#define NN 50
#define DIN 2048
#define DD 512
#define PD 64
#define FF 80
#define GG 592
#define BN (BB*NN)      // 1600

// ---- scratch slot map (f32 slots inside out ch1 slabs) ----
// slab b = out + (2b+1)*25600 ; [0,2500)=Ahat bits, [2500,6500)=rl,
// [6500,22884) = global scratch window: slot s -> slab s>>14, idx 6500+(s&16383)
#define S_MF 0          // 1600
#define S_SS 1600       // 1600
#define S_SO 3200       // 1600
#define S_PS 4800       // 1600*64  -> 107200
#define S_FS 107200     // 1600*80  -> 235200
#define S_FO 235200     // 1600*80  -> 363200  (slabs 0..22)

__device__ __forceinline__ float b2f(bf16 x){ return __bfloat162float(x); }

__device__ __forceinline__ float* sc(float* out, int s){
    return out + (size_t)((s>>14)*2+1)*25600 + 6500 + (s & 16383);
}

// Detect whether input buffers hold split f32 (bf16 pairs) or true bf16 values.
// Even-index bf16 elements of a true-bf16 N(0,1) buffer have sane exponents;
// of an f32 buffer they are uniform mantissa bits (~8% sane).
__device__ int detect_f32(const bf16* images){
    int sane=0;
    for(int k=0;k<64;k++){
        bf16 h=images[2*k];
        unsigned short u; __builtin_memcpy(&u,&h,2);
        unsigned e=(u>>7)&0xFF;
        if((u&0x7FFF)==0 || (e>=0x70 && e<=0x85)) sane++;
    }
    return (sane<48)?1:0;
}

// Load logical element i of an input buffer under either world.
__device__ __forceinline__ float LDI(const bf16* p, size_t i, int f32m){
    if(f32m){
        bf16 a=p[2*i], b=p[2*i+1];
        unsigned short lo,hi;
        __builtin_memcpy(&lo,&a,2); __builtin_memcpy(&hi,&b,2);
        unsigned v=((unsigned)hi<<16)|(unsigned)lo;
        float f; __builtin_memcpy(&f,&v,4);
        return f;
    }
    return __bfloat162float(p[i]);
}

// ---------------- K1: mask+amask, x=LN(relu(im@pre_w+b)) -> out ch0 (f32),
//                  subj/obj projections -> scratch ----------------
__global__ void k_pre(const bf16* __restrict__ images, const bf16* __restrict__ w,
                      const bf16* __restrict__ bias, const bf16* __restrict__ g,
                      const bf16* __restrict__ be,
                      const bf16* __restrict__ subj_w, const bf16* __restrict__ subj_b,
                      const bf16* __restrict__ obj_w,  const bf16* __restrict__ obj_b,
                      const bf16* __restrict__ rs_w,   const bf16* __restrict__ rf_w,
                      float* out){
    __shared__ float a[DIN];
    __shared__ float xr[DD];
    __shared__ float red[256];
    __shared__ int fm;
    int r = blockIdx.x, t = threadIdx.x;
    if(t==0) fm=detect_f32(images);
    __syncthreads();
    int F=fm;
    float s = 0.f;
    for(int k=t;k<DIN;k+=256){ float v=LDI(images,(size_t)r*DIN+k,F); a[k]=v; s+=v; }
    red[t]=s; __syncthreads();
    for(int o=128;o>0;o>>=1){ if(t<o) red[t]+=red[t+o]; __syncthreads(); }
    float m = (red[0]!=0.f)?1.f:0.f;
    if(t==0){
        *sc(out,S_MF+r)=m;
        out[(size_t)BB*2*NN*DD + r]=1.f-m;   // attention_mask (f32 0/1)
    }
    __syncthreads();
    int c0=t, c1=t+256;
    float acc0=0.f, acc1=0.f;
    for(int k=0;k<DIN;k++){
        float av=a[k];
        acc0 += av*LDI(w,(size_t)k*DD+c0,F);
        acc1 += av*LDI(w,(size_t)k*DD+c1,F);
    }
    float y0 = fmaxf(acc0 + LDI(bias,c0,F), 0.f);
    float y1 = fmaxf(acc1 + LDI(bias,c1,F), 0.f);
    red[t] = y0+y1; __syncthreads();
    for(int o=128;o>0;o>>=1){ if(t<o) red[t]+=red[t+o]; __syncthreads(); }
    float mean = red[0]/DD;
    __syncthreads();
    float d0=y0-mean, d1=y1-mean;
    red[t]=d0*d0+d1*d1; __syncthreads();
    for(int o=128;o>0;o>>=1){ if(t<o) red[t]+=red[t+o]; __syncthreads(); }
    float rstd = rsqrtf(red[0]/DD + 1e-5f);
    float xv0 = d0*rstd*LDI(g,c0,F) + LDI(be,c0,F);
    float xv1 = d1*rstd*LDI(g,c1,F) + LDI(be,c1,F);
    xr[c0]=xv0; xr[c1]=xv1;
    size_t ob = ((size_t)(r/NN)*2)*NN*DD + (size_t)(r%NN)*DD;
    out[ob+c0] = xv0;
    out[ob+c1] = xv1;
    __syncthreads();
    // subj/obj rows (f32, LDS); only projections leave the block
    float s0=0,s1=0,o0=0,o1=0;
    for(int k=0;k<DD;k++){
        float v=xr[k];
        s0+=v*LDI(subj_w,(size_t)k*DD+c0,F); s1+=v*LDI(subj_w,(size_t)k*DD+c1,F);
        o0+=v*LDI(obj_w,(size_t)k*DD+c0,F);  o1+=v*LDI(obj_w,(size_t)k*DD+c1,F);
    }
    float* xsl=a; float* xol=a+DD;   // a[] dead after pre-GEMM
    xsl[c0]=fmaxf(s0+LDI(subj_b,c0,F),0.f)*m;
    xsl[c1]=fmaxf(s1+LDI(subj_b,c1,F),0.f)*m;
    xol[c0]=fmaxf(o0+LDI(obj_b,c0,F),0.f)*m;
    xol[c1]=fmaxf(o1+LDI(obj_b,c1,F),0.f)*m;
    __syncthreads();
    float ps_=0.f, po_=0.f;
    for(int k=t;k<DD;k+=256){ ps_+=xsl[k]*LDI(rs_w,k,F); po_+=xol[k]*LDI(rs_w,k,F); }
    red[t]=ps_; __syncthreads();
    for(int o=128;o>0;o>>=1){ if(t<o) red[t]+=red[t+o]; __syncthreads(); }
    if(t==0) *sc(out,S_SS+r)=red[0];
    __syncthreads();
    red[t]=po_; __syncthreads();
    for(int o=128;o>0;o>>=1){ if(t<o) red[t]+=red[t+o]; __syncthreads(); }
    if(t==0) *sc(out,S_SO+r)=red[0];
    if(t<FF){
        float acc=0.f;
        for(int k=0;k<DD;k++) acc+=xsl[k]*LDI(rf_w,(size_t)k*FF+t,F);
        *sc(out,S_FS+r*FF+t)=acc;
    } else if(t>=128 && t<128+FF){
        int f=t-128;
        float acc=0.f;
        for(int k=0;k<DD;k++) acc+=xol[k]*LDI(rf_w,(size_t)k*FF+f,F);
        *sc(out,S_FO+r*FF+f)=acc;
    }
}

// ---------------- K2: pos_self -> scratch (f32) ----------------
__global__ void k_pos_self(const bf16* __restrict__ images, const bf16* __restrict__ sb,
                           const bf16* __restrict__ w1, const bf16* __restrict__ b1,
                           const bf16* __restrict__ g, const bf16* __restrict__ be,
                           const bf16* __restrict__ w2, const bf16* __restrict__ b2,
                           float* out){
    __shared__ float h[PD];
    __shared__ float stat[2];
    __shared__ int fm;
    int r=blockIdx.x, t=threadIdx.x;
    if(t==0) fm=detect_f32(images);
    __syncthreads();
    int F=fm;
    float acc=0.f;
    for(int q=0;q<8;q++) acc+=LDI(sb,(size_t)r*8+q,F)*LDI(w1,(size_t)q*PD+t,F);
    acc=fmaxf(acc+LDI(b1,t,F),0.f);
    h[t]=acc; __syncthreads();
    if(t==0){
        float sm=0; for(int k=0;k<PD;k++) sm+=h[k];
        float mean=sm/PD;
        float v=0; for(int k=0;k<PD;k++){float d=h[k]-mean; v+=d*d;}
        stat[0]=mean; stat[1]=rsqrtf(v/PD+1e-5f);
    }
    __syncthreads();
    float hn=(acc-stat[0])*stat[1]*LDI(g,t,F)+LDI(be,t,F);
    h[t]=hn; __syncthreads();
    float acc2=0;
    for(int k=0;k<PD;k++) acc2+=h[k]*LDI(w2,(size_t)k*PD+t,F);
    float mi=*sc(out,S_MF+r);
    *sc(out,S_PS+r*PD+t)=fmaxf(acc2+LDI(b2,t,F),0.f)*mi;
}

// ---------------- K3: fused pair loop; writes Ahat bits + rl into slab b ----------------
__global__ void k_row(const bf16* __restrict__ images, const bf16* __restrict__ bbox,
                      const bf16* __restrict__ w1, const bf16* __restrict__ b1,
                      const bf16* __restrict__ g, const bf16* __restrict__ be,
                      const bf16* __restrict__ w2, const bf16* __restrict__ b2,
                      const bf16* __restrict__ rsw, const bf16* __restrict__ rsb,
                      const bf16* __restrict__ rfw, const bf16* __restrict__ rfb,
                      float* out){
    __shared__ float pr_[PD];
    __shared__ float h[PD];
    __shared__ float red[128];
    __shared__ float stat[6];   // 0:mean 1:rstd 2:m 3:l 4:scale 5:wj
    __shared__ int fm;
    int r=blockIdx.x, t=threadIdx.x;
    int b=r/NN, i=r%NN;
    if(t==0) fm=detect_f32(images);
    __syncthreads();
    int F=fm;
    float* o1b = out + (size_t)(2*b+1)*NN*DD;
    float mi=*sc(out,S_MF+r);
    float rsbv=LDI(rsb,0,F);
    if(t==0){ stat[2]=-1e30f; stat[3]=0.f; }
    float accv=0.f;
    __syncthreads();
    for(int j=0;j<NN;j++){
        float mj=*sc(out,S_MF+b*NN+j);
        if(j==i){
            if(t<PD) pr_[t]=*sc(out,S_PS+r*PD+t);
        } else {
            size_t bbase=((size_t)r*NN+j)*8;
            if(t<PD){
                float a=0.f;
                for(int q=0;q<8;q++) a+=LDI(bbox,bbase+q,F)*LDI(w1,(size_t)q*PD+t,F);
                h[t]=fmaxf(a+LDI(b1,t,F),0.f);
            }
            __syncthreads();
            if(t==0){
                float sm=0; for(int k=0;k<PD;k++) sm+=h[k];
                float mean=sm/PD;
                float v=0; for(int k=0;k<PD;k++){float d=h[k]-mean; v+=d*d;}
                stat[0]=mean; stat[1]=rsqrtf(v/PD+1e-5f);
            }
            __syncthreads();
            if(t<PD) pr_[t]=(h[t]-stat[0])*stat[1]*LDI(g,t,F)+LDI(be,t,F);
            __syncthreads();
            if(t<PD){
                float a=0.f;
                for(int k=0;k<PD;k++) a+=pr_[k]*LDI(w2,(size_t)k*PD+t,F);
                h[t]=fmaxf(a+LDI(b2,t,F),0.f)*mi*mj;
            }
            __syncthreads();
            if(t<PD) pr_[t]=h[t];
        }
        __syncthreads();
        red[t]=(t<PD)? pr_[t]*LDI(rsw,DD+t,F) : 0.f;
        __syncthreads();
        for(int o=64;o>0;o>>=1){ if(t<o) red[t]+=red[t+o]; __syncthreads(); }
        if(t==0){
            float base=(j==i)? *sc(out,S_SS+r) : *sc(out,S_SO+b*NN+j);
            float lgj=mi*base + red[0] + rsbv;
            bool af=(j==i) || (lgj>0.f && mi>0.5f && mj>0.5f);
            o1b[i*NN+j]=af?1.f:0.f;                      // Ahat bit
            float lgm=(mi>0.5f && mj>0.5f)? lgj : -1e9f;
            float mnew=fmaxf(stat[2],lgm);
            float scl=expf(stat[2]-mnew);
            float wj=expf(lgm-mnew);
            stat[3]=stat[3]*scl+wj; stat[2]=mnew; stat[4]=scl; stat[5]=wj;
        }
        __syncthreads();
        if(t<FF){
            float fp=0.f;
            for(int k=0;k<PD;k++) fp+=pr_[k]*LDI(rfw,(size_t)(DD+k)*FF+t,F);
            float fb=(j==i)? *sc(out,S_FS+r*FF+t) : *sc(out,S_FO+(b*NN+j)*FF+t);
            float fd=fmaxf(mi*fb+fp+LDI(rfb,t,F),0.f);
            accv=accv*stat[4]+stat[5]*fd;
        }
        __syncthreads();
    }
    if(t<FF) o1b[2500 + i*FF + t]=accv/stat[3]*mi;       // rl
}

// ---------------- K4: fused GCN 1+2+3, one block per image, final ch1 ----------------
__global__ void k_fuse123(const bf16* __restrict__ images,
                          const bf16* __restrict__ W1, const bf16* __restrict__ B1,
                          const bf16* __restrict__ W2, const bf16* __restrict__ B2,
                          const bf16* __restrict__ W3, const bf16* __restrict__ B3,
                          float* out){
    __shared__ bf16 x1s[NN*GG];        // 59,200 B
    __shared__ float rowb[GG];
    __shared__ unsigned bits[NN*2];
    __shared__ float dinv[64];
    __shared__ int fm;
    int b=blockIdx.x, t=threadIdx.x;
    if(t==0) fm=detect_f32(images);
    __syncthreads();
    int F=fm;
    float* o1b = out + (size_t)(2*b+1)*NN*DD;
    const float* x0 = out + (size_t)(2*b)*NN*DD;
    if(t<NN){
        unsigned m0=0,m1=0;
        for(int j=0;j<NN;j++){
            if(o1b[t*NN+j]>0.5f){ if(j<32) m0|=(1u<<j); else m1|=(1u<<(j-32)); }
        }
        bits[t*2]=m0; bits[t*2+1]=m1;
    }
    __syncthreads();
    if(t<NN){
        float dg=0.f;
        for(int i=0;i<NN;i++) if((bits[i*2+(t>>5)]>>(t&31))&1) dg+=1.f;
        dinv[t]=rsqrtf(dg);
    }
    __syncthreads();
    // phase 1: x1 into LDS (bf16)
    for(int tile=0;tile<3;tile++){
        int c=tile*256+t;
        float acc[NN];
        for(int j=0;j<NN;j++) acc[j]=0.f;
        for(int i=0;i<NN;i++){
            for(int k=t;k<DD;k+=256) rowb[k]=x0[(size_t)i*DD+k];
            if(t<GG-DD) rowb[DD+t]=o1b[2500+i*FF+t];
            __syncthreads();
            if(c<GG){
                float ti=0.f;
                for(int k=0;k<GG;k++) ti+=rowb[k]*LDI(W1,(size_t)k*GG+c,F);
                float wdi=dinv[i]*ti;
                for(int j=0;j<NN;j++)
                    if((bits[i*2+(j>>5)]>>(j&31))&1) acc[j]+=wdi*dinv[j];
            }
            __syncthreads();
        }
        if(c<GG){
            float bb=LDI(B1,c,F);
            for(int j=0;j<NN;j++) x1s[j*GG+c]=__float2bfloat16(fmaxf(acc[j]+bb,0.f));
        }
        __syncthreads();
    }
    // phase 2: x2 -> slab (staging consumed)
    for(int tile=0;tile<2;tile++){
        int c=tile*256+t;
        float acc[NN];
        for(int j=0;j<NN;j++) acc[j]=0.f;
        for(int i=0;i<NN;i++){
            float ti=0.f;
            for(int k=0;k<GG;k++) ti+=b2f(x1s[i*GG+k])*LDI(W2,(size_t)k*DD+c,F);
            float wdi=dinv[i]*ti;
            for(int j=0;j<NN;j++)
                if((bits[i*2+(j>>5)]>>(j&31))&1) acc[j]+=wdi*dinv[j];
        }
        float bb=LDI(B2,c,F);
        for(int j=0;j<NN;j++) o1b[(size_t)j*DD+c]=fmaxf(acc[j]+bb,0.f);
    }
    __threadfence_block();
    __syncthreads();
    // phase 3: x3 in-place on slab
    int c0=t, c1=t+256;
    float acc0[NN], acc1[NN];
    for(int j=0;j<NN;j++){ acc0[j]=0.f; acc1[j]=0.f; }
    for(int i=0;i<NN;i++){
        for(int k=t;k<DD;k+=256) rowb[k]=o1b[(size_t)i*DD+k];
        __syncthreads();
        float t0=0.f, t1=0.f;
        for(int k=0;k<DD;k++){
            float v=rowb[k];
            t0+=v*LDI(W3,(size_t)k*DD+c0,F);
            t1+=v*LDI(W3,(size_t)k*DD+c1,F);
        }
        float di=dinv[i];
        for(int j=0;j<NN;j++)
            if((bits[i*2+(j>>5)]>>(j&31))&1){ float wv=di*dinv[j]; acc0[j]+=wv*t0; acc1[j]+=wv*t1; }
        __syncthreads();
    }
    float bb0=LDI(B3,c0,F), bb1=LDI(B3,c1,F);
    for(int j=0;j<NN;j++){
        o1b[(size_t)j*DD+c0]=fmaxf(acc0[j]+bb0,0.f);
        o1b[(size_t)j*DD+c1]=fmaxf(acc1[j]+bb1,0.f);
    }
}

extern "C" void kernel_launch(void* const* d_in, const int* in_sizes, int n_in,
                              void* d_out, int out_size, void* d_ws, size_t ws_size,
                              hipStream_t stream) {
    const bf16* images  = (const bf16*)d_in[0];
    const bf16* selfbbox= (const bf16*)d_in[1];
    const bf16* bbox    = (const bf16*)d_in[2];
    const bf16* pre_w   = (const bf16*)d_in[3];
    const bf16* pre_b   = (const bf16*)d_in[4];
    const bf16* pre_g   = (const bf16*)d_in[5];
    const bf16* pre_be  = (const bf16*)d_in[6];
    const bf16* subj_w  = (const bf16*)d_in[7];
    const bf16* subj_b  = (const bf16*)d_in[8];
    const bf16* obj_w   = (const bf16*)d_in[9];
    const bf16* obj_b   = (const bf16*)d_in[10];
    const bf16* ps1_w   = (const bf16*)d_in[11];
    const bf16* ps1_b   = (const bf16*)d_in[12];
    const bf16* ps_g    = (const bf16*)d_in[13];
    const bf16* ps_be   = (const bf16*)d_in[14];
    const bf16* ps2_w   = (const bf16*)d_in[15];
    const bf16* ps2_b   = (const bf16*)d_in[16];
    const bf16* pr1_w   = (const bf16*)d_in[17];
    const bf16* pr1_b   = (const bf16*)d_in[18];
    const bf16* pr_g    = (const bf16*)d_in[19];
    const bf16* pr_be   = (const bf16*)d_in[20];
    const bf16* pr2_w   = (const bf16*)d_in[21];
    const bf16* pr2_b   = (const bf16*)d_in[22];
    const bf16* rs_w    = (const bf16*)d_in[23];
    const bf16* rs_b    = (const bf16*)d_in[24];
    const bf16* rf_w    = (const bf16*)d_in[25];
    const bf16* rf_b    = (const bf16*)d_in[26];
    const bf16* g1_w    = (const bf16*)d_in[27];
    const bf16* g1_b    = (const bf16*)d_in[28];
    const bf16* g2_w    = (const bf16*)d_in[29];
    const bf16* g2_b    = (const bf16*)d_in[30];
    const bf16* g3_w    = (const bf16*)d_in[31];
    const bf16* g3_b    = (const bf16*)d_in[32];

    float* out = (float*)d_out;   // output is f32 (reference output dtype); d_ws unused

    k_pre<<<BN, 256, 0, stream>>>(images, pre_w, pre_b, pre_g, pre_be,
                                  subj_w, subj_b, obj_w, obj_b, rs_w, rf_w, out);
    k_pos_self<<<BN, PD, 0, stream>>>(images, selfbbox, ps1_w, ps1_b, ps_g, ps_be,
                                      ps2_w, ps2_b, out);
    k_row<<<BN, 128, 0, stream>>>(images, bbox, pr1_w, pr1_b, pr_g, pr_be, pr2_w, pr2_b,
                                  rs_w, rs_b, rf_w, rf_b, out);
    k_fuse123<<<BB, 256, 0, stream>>>(images, g1_w, g1_b, g2_w, g2_b, g3_w, g3_b, out);
}

// Round 13
// 4985.049 us; speedup vs baseline: 2.4058x; 2.4058x over previous
//
#include <hip/hip_runtime.h>
#include <hip/hip_bf16.h>

typedef __hip_bfloat16 bf16;

#define BB 32
#define NN 50
#define DIN 2048
#define DD 512
#define PD 64
#define FF 80
#define GG 592
#define BN (BB*NN)      // 1600

// ---- scratch slot map (f32 slots inside out ch1 slabs) ----
// slab b = out + (2b+1)*25600 ; [0,2500)=Ahat bits, [2500,6500)=rl,
// [6500,...) = scratch window: slot s -> slab s>>14, idx 6500+(s&16383)
#define S_MF 0          // 1600
#define S_SS 1600       // 1600
#define S_SO 3200       // 1600
#define S_PS 4800       // 1600*64  -> 107200
#define S_FS 107200     // 1600*80  -> 235200
#define S_FO 235200     // 1600*80  -> 363200

__device__ __forceinline__ float b2f(bf16 x){ return __bfloat162float(x); }

__device__ __forceinline__ float* sc(float* out, int s){
    return out + (size_t)((s>>14)*2+1)*25600 + 6500 + (s & 16383);
}

// Detect whether input buffers hold split f32 (bf16 pairs) or true bf16 values.
__device__ int detect_f32(const bf16* images){
    int sane=0;
    for(int k=0;k<64;k++){
        bf16 h=images[2*k];
        unsigned short u; __builtin_memcpy(&u,&h,2);
        unsigned e=(u>>7)&0xFF;
        if((u&0x7FFF)==0 || (e>=0x70 && e<=0x85)) sane++;
    }
    return (sane<48)?1:0;
}

// Load logical element i of an input buffer under either world.
__device__ __forceinline__ float LDI(const bf16* p, size_t i, int f32m){
    if(f32m){
        bf16 a=p[2*i], b=p[2*i+1];
        unsigned short lo,hi;
        __builtin_memcpy(&lo,&a,2); __builtin_memcpy(&hi,&b,2);
        unsigned v=((unsigned)hi<<16)|(unsigned)lo;
        float f; __builtin_memcpy(&f,&v,4);
        return f;
    }
    return __bfloat162float(p[i]);
}

// ---------------- K1: mask+amask, x=LN(relu(im@pre_w+b)) -> out ch0 (f32),
//                  subj/obj projections -> scratch ----------------
__global__ void k_pre(const bf16* __restrict__ images, const bf16* __restrict__ w,
                      const bf16* __restrict__ bias, const bf16* __restrict__ g,
                      const bf16* __restrict__ be,
                      const bf16* __restrict__ subj_w, const bf16* __restrict__ subj_b,
                      const bf16* __restrict__ obj_w,  const bf16* __restrict__ obj_b,
                      const bf16* __restrict__ rs_w,   const bf16* __restrict__ rf_w,
                      float* out){
    __shared__ float a[DIN];
    __shared__ float xr[DD];
    __shared__ float red[256];
    __shared__ int fm;
    int r = blockIdx.x, t = threadIdx.x;
    if(t==0) fm=detect_f32(images);
    __syncthreads();
    int F=fm;
    float s = 0.f;
    for(int k=t;k<DIN;k+=256){ float v=LDI(images,(size_t)r*DIN+k,F); a[k]=v; s+=v; }
    red[t]=s; __syncthreads();
    for(int o=128;o>0;o>>=1){ if(t<o) red[t]+=red[t+o]; __syncthreads(); }
    float m = (red[0]!=0.f)?1.f:0.f;
    if(t==0){
        *sc(out,S_MF+r)=m;
        out[(size_t)BB*2*NN*DD + r]=1.f-m;   // attention_mask (f32 0/1)
    }
    __syncthreads();
    int c0=t, c1=t+256;
    float acc0=0.f, acc1=0.f;
    for(int k=0;k<DIN;k++){
        float av=a[k];
        acc0 += av*LDI(w,(size_t)k*DD+c0,F);
        acc1 += av*LDI(w,(size_t)k*DD+c1,F);
    }
    float y0 = fmaxf(acc0 + LDI(bias,c0,F), 0.f);
    float y1 = fmaxf(acc1 + LDI(bias,c1,F), 0.f);
    red[t] = y0+y1; __syncthreads();
    for(int o=128;o>0;o>>=1){ if(t<o) red[t]+=red[t+o]; __syncthreads(); }
    float mean = red[0]/DD;
    __syncthreads();
    float d0=y0-mean, d1=y1-mean;
    red[t]=d0*d0+d1*d1; __syncthreads();
    for(int o=128;o>0;o>>=1){ if(t<o) red[t]+=red[t+o]; __syncthreads(); }
    float rstd = rsqrtf(red[0]/DD + 1e-5f);
    float xv0 = d0*rstd*LDI(g,c0,F) + LDI(be,c0,F);
    float xv1 = d1*rstd*LDI(g,c1,F) + LDI(be,c1,F);
    xr[c0]=xv0; xr[c1]=xv1;
    size_t ob = ((size_t)(r/NN)*2)*NN*DD + (size_t)(r%NN)*DD;
    out[ob+c0] = xv0;
    out[ob+c1] = xv1;
    __syncthreads();
    float s0=0,s1=0,o0=0,o1=0;
    for(int k=0;k<DD;k++){
        float v=xr[k];
        s0+=v*LDI(subj_w,(size_t)k*DD+c0,F); s1+=v*LDI(subj_w,(size_t)k*DD+c1,F);
        o0+=v*LDI(obj_w,(size_t)k*DD+c0,F);  o1+=v*LDI(obj_w,(size_t)k*DD+c1,F);
    }
    float* xsl=a; float* xol=a+DD;
    xsl[c0]=fmaxf(s0+LDI(subj_b,c0,F),0.f)*m;
    xsl[c1]=fmaxf(s1+LDI(subj_b,c1,F),0.f)*m;
    xol[c0]=fmaxf(o0+LDI(obj_b,c0,F),0.f)*m;
    xol[c1]=fmaxf(o1+LDI(obj_b,c1,F),0.f)*m;
    __syncthreads();
    float ps_=0.f, po_=0.f;
    for(int k=t;k<DD;k+=256){ ps_+=xsl[k]*LDI(rs_w,k,F); po_+=xol[k]*LDI(rs_w,k,F); }
    red[t]=ps_; __syncthreads();
    for(int o=128;o>0;o>>=1){ if(t<o) red[t]+=red[t+o]; __syncthreads(); }
    if(t==0) *sc(out,S_SS+r)=red[0];
    __syncthreads();
    red[t]=po_; __syncthreads();
    for(int o=128;o>0;o>>=1){ if(t<o) red[t]+=red[t+o]; __syncthreads(); }
    if(t==0) *sc(out,S_SO+r)=red[0];
    if(t<FF){
        float acc=0.f;
        for(int k=0;k<DD;k++) acc+=xsl[k]*LDI(rf_w,(size_t)k*FF+t,F);
        *sc(out,S_FS+r*FF+t)=acc;
    } else if(t>=128 && t<128+FF){
        int f=t-128;
        float acc=0.f;
        for(int k=0;k<DD;k++) acc+=xol[k]*LDI(rf_w,(size_t)k*FF+f,F);
        *sc(out,S_FO+r*FF+f)=acc;
    }
}

// ---------------- K2: pos_self -> scratch (f32) ----------------
__global__ void k_pos_self(const bf16* __restrict__ images, const bf16* __restrict__ sb,
                           const bf16* __restrict__ w1, const bf16* __restrict__ b1,
                           const bf16* __restrict__ g, const bf16* __restrict__ be,
                           const bf16* __restrict__ w2, const bf16* __restrict__ b2,
                           float* out){
    __shared__ float h[PD];
    __shared__ float stat[2];
    __shared__ int fm;
    int r=blockIdx.x, t=threadIdx.x;
    if(t==0) fm=detect_f32(images);
    __syncthreads();
    int F=fm;
    float acc=0.f;
    for(int q=0;q<8;q++) acc+=LDI(sb,(size_t)r*8+q,F)*LDI(w1,(size_t)q*PD+t,F);
    acc=fmaxf(acc+LDI(b1,t,F),0.f);
    h[t]=acc; __syncthreads();
    if(t==0){
        float sm=0; for(int k=0;k<PD;k++) sm+=h[k];
        float mean=sm/PD;
        float v=0; for(int k=0;k<PD;k++){float d=h[k]-mean; v+=d*d;}
        stat[0]=mean; stat[1]=rsqrtf(v/PD+1e-5f);
    }
    __syncthreads();
    float hn=(acc-stat[0])*stat[1]*LDI(g,t,F)+LDI(be,t,F);
    h[t]=hn; __syncthreads();
    float acc2=0;
    for(int k=0;k<PD;k++) acc2+=h[k]*LDI(w2,(size_t)k*PD+t,F);
    float mi=*sc(out,S_MF+r);
    *sc(out,S_PS+r*PD+t)=fmaxf(acc2+LDI(b2,t,F),0.f)*mi;
}

// ---------------- K3: fused pair loop; writes Ahat bits + rl into slab b ----------------
__global__ void k_row(const bf16* __restrict__ images, const bf16* __restrict__ bbox,
                      const bf16* __restrict__ w1, const bf16* __restrict__ b1,
                      const bf16* __restrict__ g, const bf16* __restrict__ be,
                      const bf16* __restrict__ w2, const bf16* __restrict__ b2,
                      const bf16* __restrict__ rsw, const bf16* __restrict__ rsb,
                      const bf16* __restrict__ rfw, const bf16* __restrict__ rfb,
                      float* out){
    __shared__ float pr_[PD];
    __shared__ float h[PD];
    __shared__ float red[128];
    __shared__ float stat[6];
    __shared__ int fm;
    int r=blockIdx.x, t=threadIdx.x;
    int b=r/NN, i=r%NN;
    if(t==0) fm=detect_f32(images);
    __syncthreads();
    int F=fm;
    float* o1b = out + (size_t)(2*b+1)*NN*DD;
    float mi=*sc(out,S_MF+r);
    float rsbv=LDI(rsb,0,F);
    if(t==0){ stat[2]=-1e30f; stat[3]=0.f; }
    float accv=0.f;
    __syncthreads();
    for(int j=0;j<NN;j++){
        float mj=*sc(out,S_MF+b*NN+j);
        if(j==i){
            if(t<PD) pr_[t]=*sc(out,S_PS+r*PD+t);
        } else {
            size_t bbase=((size_t)r*NN+j)*8;
            if(t<PD){
                float a=0.f;
                for(int q=0;q<8;q++) a+=LDI(bbox,bbase+q,F)*LDI(w1,(size_t)q*PD+t,F);
                h[t]=fmaxf(a+LDI(b1,t,F),0.f);
            }
            __syncthreads();
            if(t==0){
                float sm=0; for(int k=0;k<PD;k++) sm+=h[k];
                float mean=sm/PD;
                float v=0; for(int k=0;k<PD;k++){float d=h[k]-mean; v+=d*d;}
                stat[0]=mean; stat[1]=rsqrtf(v/PD+1e-5f);
            }
            __syncthreads();
            if(t<PD) pr_[t]=(h[t]-stat[0])*stat[1]*LDI(g,t,F)+LDI(be,t,F);
            __syncthreads();
            if(t<PD){
                float a=0.f;
                for(int k=0;k<PD;k++) a+=pr_[k]*LDI(w2,(size_t)k*PD+t,F);
                h[t]=fmaxf(a+LDI(b2,t,F),0.f)*mi*mj;
            }
            __syncthreads();
            if(t<PD) pr_[t]=h[t];
        }
        __syncthreads();
        red[t]=(t<PD)? pr_[t]*LDI(rsw,DD+t,F) : 0.f;
        __syncthreads();
        for(int o=64;o>0;o>>=1){ if(t<o) red[t]+=red[t+o]; __syncthreads(); }
        if(t==0){
            float base=(j==i)? *sc(out,S_SS+r) : *sc(out,S_SO+b*NN+j);
            float lgj=mi*base + red[0] + rsbv;
            bool af=(j==i) || (lgj>0.f && mi>0.5f && mj>0.5f);
            o1b[i*NN+j]=af?1.f:0.f;                      // Ahat bit
            float lgm=(mi>0.5f && mj>0.5f)? lgj : -1e9f;
            float mnew=fmaxf(stat[2],lgm);
            float scl=expf(stat[2]-mnew);
            float wj=expf(lgm-mnew);
            stat[3]=stat[3]*scl+wj; stat[2]=mnew; stat[4]=scl; stat[5]=wj;
        }
        __syncthreads();
        if(t<FF){
            float fp=0.f;
            for(int k=0;k<PD;k++) fp+=pr_[k]*LDI(rfw,(size_t)(DD+k)*FF+t,F);
            float fb=(j==i)? *sc(out,S_FS+r*FF+t) : *sc(out,S_FO+(b*NN+j)*FF+t);
            float fd=fmaxf(mi*fb+fp+LDI(rfb,t,F),0.f);
            accv=accv*stat[4]+stat[5]*fd;
        }
        __syncthreads();
    }
    if(t<FF) o1b[2500 + i*FF + t]=accv/stat[3]*mi;       // rl
}

// ---- shared helper: load Ahat bits + dinv into LDS (caller syncs) ----
__device__ void load_adj(const float* o1b, unsigned* bits, float* dinv, int t){
    if(t<NN){
        unsigned m0=0,m1=0;
        for(int j=0;j<NN;j++)
            if(o1b[t*NN+j]>0.5f){ if(j<32) m0|=(1u<<j); else m1|=(1u<<(j-32)); }
        bits[t*2]=m0; bits[t*2+1]=m1;
    }
    __syncthreads();
    if(t<NN){
        float dg=0.f;
        for(int i=0;i<NN;i++) if((bits[i*2+(t>>5)]>>(t&31))&1) dg+=1.f;
        dinv[t]=rsqrtf(dg);
    }
}

// ---------------- KG1: GCN layer 1 (96 blocks: image x c-tile) ----------------
// x1[b][j][c] (bf16) -> slab-b window, layout j*GG+c at (bf16*)(o1b+6500)
__global__ void kg1(const bf16* __restrict__ images, const bf16* __restrict__ W1,
                    const bf16* __restrict__ B1, float* out){
    __shared__ bf16 xxs[NN*GG];        // 59,200 B
    __shared__ unsigned bits[NN*2];
    __shared__ float dinv[64];
    __shared__ int fm;
    int blk=blockIdx.x, t=threadIdx.x;
    int b=blk/3, tile=blk%3;
    if(t==0) fm=detect_f32(images);
    float* o1b = out + (size_t)(2*b+1)*NN*DD;
    const float* x0 = out + (size_t)(2*b)*NN*DD;
    bf16* win = (bf16*)(o1b + 6500);
    load_adj(o1b, bits, dinv, t);
    for(int idx=t; idx<NN*DD; idx+=256){
        int i=idx>>9, k=idx&511;
        xxs[i*GG+k]=__float2bfloat16(x0[(size_t)i*DD+k]);
    }
    for(int idx=t; idx<NN*FF; idx+=256){
        int i=idx/FF, k=idx-i*FF;
        xxs[i*GG+DD+k]=__float2bfloat16(o1b[2500+i*FF+k]);
    }
    __syncthreads();
    int F=fm;
    int c=tile*256+t;
    if(c>=GG) return;
    float oacc[NN];
    #pragma unroll
    for(int j=0;j<NN;j++) oacc[j]=0.f;
    for(int i0=0;i0<NN;i0+=10){
        float tac[10];
        #pragma unroll
        for(int u=0;u<10;u++) tac[u]=0.f;
        for(int k=0;k<GG;k++){
            float w=LDI(W1,(size_t)k*GG+c,F);
            #pragma unroll
            for(int u=0;u<10;u++) tac[u]+=b2f(xxs[(i0+u)*GG+k])*w;
        }
        #pragma unroll
        for(int u=0;u<10;u++){
            int i=i0+u;
            float v=dinv[i]*tac[u];
            for(int j=0;j<NN;j++)
                if((bits[i*2+(j>>5)]>>(j&31))&1) oacc[j]+=v*dinv[j];
        }
    }
    float bb=LDI(B1,c,F);
    for(int j=0;j<NN;j++)
        win[j*GG+c]=__float2bfloat16(fmaxf(oacc[j]+bb,0.f));
}

// ---------------- KG2: GCN layer 2 (32 blocks; in-place on slab window) ----------------
__global__ void kg2(const bf16* __restrict__ images, const bf16* __restrict__ W2,
                    const bf16* __restrict__ B2, float* out){
    __shared__ bf16 x1s[NN*GG];        // 59,200 B
    __shared__ unsigned bits[NN*2];
    __shared__ float dinv[64];
    __shared__ int fm;
    int b=blockIdx.x, t=threadIdx.x;
    if(t==0) fm=detect_f32(images);
    float* o1b = out + (size_t)(2*b+1)*NN*DD;
    bf16* win = (bf16*)(o1b + 6500);
    load_adj(o1b, bits, dinv, t);
    for(int idx=t; idx<NN*GG; idx+=256) x1s[idx]=win[idx];
    __syncthreads();
    int F=fm;
    for(int pass=0;pass<2;pass++){
        int c=pass*256+t;
        float oacc[NN];
        #pragma unroll
        for(int j=0;j<NN;j++) oacc[j]=0.f;
        for(int i0=0;i0<NN;i0+=10){
            float tac[10];
            #pragma unroll
            for(int u=0;u<10;u++) tac[u]=0.f;
            for(int k=0;k<GG;k++){
                float w=LDI(W2,(size_t)k*DD+c,F);
                #pragma unroll
                for(int u=0;u<10;u++) tac[u]+=b2f(x1s[(i0+u)*GG+k])*w;
            }
            #pragma unroll
            for(int u=0;u<10;u++){
                int i=i0+u;
                float v=dinv[i]*tac[u];
                for(int j=0;j<NN;j++)
                    if((bits[i*2+(j>>5)]>>(j&31))&1) oacc[j]+=v*dinv[j];
            }
        }
        float bb=LDI(B2,c,F);
        for(int j=0;j<NN;j++)
            win[j*DD+c]=__float2bfloat16(fmaxf(oacc[j]+bb,0.f));   // x2 over x1 (staged)
        __syncthreads();
    }
}

// ---------------- KG3: GCN layer 3 (32 blocks; final f32 ch1) ----------------
__global__ void kg3(const bf16* __restrict__ images, const bf16* __restrict__ W3,
                    const bf16* __restrict__ B3, float* out){
    __shared__ bf16 x2s[NN*DD];        // 51,200 B
    __shared__ unsigned bits[NN*2];
    __shared__ float dinv[64];
    __shared__ int fm;
    int b=blockIdx.x, t=threadIdx.x;
    if(t==0) fm=detect_f32(images);
    float* o1b = out + (size_t)(2*b+1)*NN*DD;
    bf16* win = (bf16*)(o1b + 6500);
    load_adj(o1b, bits, dinv, t);
    for(int idx=t; idx<NN*DD; idx+=256) x2s[idx]=win[idx];
    __syncthreads();
    int F=fm;
    float res0[NN], res1[NN];
    for(int pass=0;pass<2;pass++){
        int c=pass*256+t;
        float oacc[NN];
        #pragma unroll
        for(int j=0;j<NN;j++) oacc[j]=0.f;
        for(int i0=0;i0<NN;i0+=10){
            float tac[10];
            #pragma unroll
            for(int u=0;u<10;u++) tac[u]=0.f;
            for(int k=0;k<DD;k++){
                float w=LDI(W3,(size_t)k*DD+c,F);
                #pragma unroll
                for(int u=0;u<10;u++) tac[u]+=b2f(x2s[(i0+u)*DD+k])*w;
            }
            #pragma unroll
            for(int u=0;u<10;u++){
                int i=i0+u;
                float v=dinv[i]*tac[u];
                for(int j=0;j<NN;j++)
                    if((bits[i*2+(j>>5)]>>(j&31))&1) oacc[j]+=v*dinv[j];
            }
        }
        float bb=LDI(B3,c,F);
        if(pass==0) for(int j=0;j<NN;j++) res0[j]=fmaxf(oacc[j]+bb,0.f);
        else        for(int j=0;j<NN;j++) res1[j]=fmaxf(oacc[j]+bb,0.f);
    }
    __syncthreads();   // all LDS reads done before overwriting the slab
    for(int j=0;j<NN;j++){
        o1b[(size_t)j*DD + t]       = res0[j];
        o1b[(size_t)j*DD + 256 + t] = res1[j];
    }
}

extern "C" void kernel_launch(void* const* d_in, const int* in_sizes, int n_in,
                              void* d_out, int out_size, void* d_ws, size_t ws_size,
                              hipStream_t stream) {
    const bf16* images  = (const bf16*)d_in[0];
    const bf16* selfbbox= (const bf16*)d_in[1];
    const bf16* bbox    = (const bf16*)d_in[2];
    const bf16* pre_w   = (const bf16*)d_in[3];
    const bf16* pre_b   = (const bf16*)d_in[4];
    const bf16* pre_g   = (const bf16*)d_in[5];
    const bf16* pre_be  = (const bf16*)d_in[6];
    const bf16* subj_w  = (const bf16*)d_in[7];
    const bf16* subj_b  = (const bf16*)d_in[8];
    const bf16* obj_w   = (const bf16*)d_in[9];
    const bf16* obj_b   = (const bf16*)d_in[10];
    const bf16* ps1_w   = (const bf16*)d_in[11];
    const bf16* ps1_b   = (const bf16*)d_in[12];
    const bf16* ps_g    = (const bf16*)d_in[13];
    const bf16* ps_be   = (const bf16*)d_in[14];
    const bf16* ps2_w   = (const bf16*)d_in[15];
    const bf16* ps2_b   = (const bf16*)d_in[16];
    const bf16* pr1_w   = (const bf16*)d_in[17];
    const bf16* pr1_b   = (const bf16*)d_in[18];
    const bf16* pr_g    = (const bf16*)d_in[19];
    const bf16* pr_be   = (const bf16*)d_in[20];
    const bf16* pr2_w   = (const bf16*)d_in[21];
    const bf16* pr2_b   = (const bf16*)d_in[22];
    const bf16* rs_w    = (const bf16*)d_in[23];
    const bf16* rs_b    = (const bf16*)d_in[24];
    const bf16* rf_w    = (const bf16*)d_in[25];
    const bf16* rf_b    = (const bf16*)d_in[26];
    const bf16* g1_w    = (const bf16*)d_in[27];
    const bf16* g1_b    = (const bf16*)d_in[28];
    const bf16* g2_w    = (const bf16*)d_in[29];
    const bf16* g2_b    = (const bf16*)d_in[30];
    const bf16* g3_w    = (const bf16*)d_in[31];
    const bf16* g3_b    = (const bf16*)d_in[32];

    float* out = (float*)d_out;   // f32 output; d_ws unused

    k_pre<<<BN, 256, 0, stream>>>(images, pre_w, pre_b, pre_g, pre_be,
                                  subj_w, subj_b, obj_w, obj_b, rs_w, rf_w, out);
    k_pos_self<<<BN, PD, 0, stream>>>(images, selfbbox, ps1_w, ps1_b, ps_g, ps_be,
                                      ps2_w, ps2_b, out);
    k_row<<<BN, 128, 0, stream>>>(images, bbox, pr1_w, pr1_b, pr_g, pr_be, pr2_w, pr2_b,
                                  rs_w, rs_b, rf_w, rf_b, out);
    kg1<<<BB*3, 256, 0, stream>>>(images, g1_w, g1_b, out);
    kg2<<<BB, 256, 0, stream>>>(images, g2_w, g2_b, out);
    kg3<<<BB, 256, 0, stream>>>(images, g3_w, g3_b, out);
}

// Round 14
// 1603.455 us; speedup vs baseline: 7.4794x; 3.1089x over previous
//
#include <hip/hip_runtime.h>
#include <hip/hip_bf16.h>

typedef __hip_bfloat16 bf16;

#define BB 32
#define NN 50
#define DIN 2048
#define DD 512
#define PD 64
#define FF 80
#define GG 592
#define BN (BB*NN)      // 1600

// ---- scratch slot map (f32 slots inside out ch1 slabs) ----
#define S_MF 0          // 1600
#define S_SS 1600       // 1600
#define S_SO 3200       // 1600
#define S_PS 4800       // 1600*64  -> 107200
#define S_FS 107200     // 1600*80  -> 235200
#define S_FO 235200     // 1600*80  -> 363200

__device__ __forceinline__ float b2f(bf16 x){ return __bfloat162float(x); }

__device__ __forceinline__ float* sc(float* out, int s){
    return out + (size_t)((s>>14)*2+1)*25600 + 6500 + (s & 16383);
}

__device__ int detect_f32(const bf16* images){
    int sane=0;
    for(int k=0;k<64;k++){
        bf16 h=images[2*k];
        unsigned short u; __builtin_memcpy(&u,&h,2);
        unsigned e=(u>>7)&0xFF;
        if((u&0x7FFF)==0 || (e>=0x70 && e<=0x85)) sane++;
    }
    return (sane<48)?1:0;
}

__device__ __forceinline__ float LDI(const bf16* p, size_t i, int f32m){
    if(f32m){
        bf16 a=p[2*i], b=p[2*i+1];
        unsigned short lo,hi;
        __builtin_memcpy(&lo,&a,2); __builtin_memcpy(&hi,&b,2);
        unsigned v=((unsigned)hi<<16)|(unsigned)lo;
        float f; __builtin_memcpy(&f,&v,4);
        return f;
    }
    return __bfloat162float(p[i]);
}

// ---------------- K1: mask+amask, x=LN(relu(im@pre_w+b)) -> out ch0 (f32),
//                  subj/obj projections -> scratch ----------------
__global__ void k_pre(const bf16* __restrict__ images, const bf16* __restrict__ w,
                      const bf16* __restrict__ bias, const bf16* __restrict__ g,
                      const bf16* __restrict__ be,
                      const bf16* __restrict__ subj_w, const bf16* __restrict__ subj_b,
                      const bf16* __restrict__ obj_w,  const bf16* __restrict__ obj_b,
                      const bf16* __restrict__ rs_w,   const bf16* __restrict__ rf_w,
                      float* out){
    __shared__ float a[DIN];
    __shared__ float xr[DD];
    __shared__ float red[256];
    __shared__ int fm;
    int r = blockIdx.x, t = threadIdx.x;
    if(t==0) fm=detect_f32(images);
    __syncthreads();
    int F=fm;
    float s = 0.f;
    for(int k=t;k<DIN;k+=256){ float v=LDI(images,(size_t)r*DIN+k,F); a[k]=v; s+=v; }
    red[t]=s; __syncthreads();
    for(int o=128;o>0;o>>=1){ if(t<o) red[t]+=red[t+o]; __syncthreads(); }
    float m = (red[0]!=0.f)?1.f:0.f;
    if(t==0){
        *sc(out,S_MF+r)=m;
        out[(size_t)BB*2*NN*DD + r]=1.f-m;   // attention_mask (f32 0/1)
    }
    __syncthreads();
    int c0=t, c1=t+256;
    float acc0=0.f, acc1=0.f;
    for(int k=0;k<DIN;k++){
        float av=a[k];
        acc0 += av*LDI(w,(size_t)k*DD+c0,F);
        acc1 += av*LDI(w,(size_t)k*DD+c1,F);
    }
    float y0 = fmaxf(acc0 + LDI(bias,c0,F), 0.f);
    float y1 = fmaxf(acc1 + LDI(bias,c1,F), 0.f);
    red[t] = y0+y1; __syncthreads();
    for(int o=128;o>0;o>>=1){ if(t<o) red[t]+=red[t+o]; __syncthreads(); }
    float mean = red[0]/DD;
    __syncthreads();
    float d0=y0-mean, d1=y1-mean;
    red[t]=d0*d0+d1*d1; __syncthreads();
    for(int o=128;o>0;o>>=1){ if(t<o) red[t]+=red[t+o]; __syncthreads(); }
    float rstd = rsqrtf(red[0]/DD + 1e-5f);
    float xv0 = d0*rstd*LDI(g,c0,F) + LDI(be,c0,F);
    float xv1 = d1*rstd*LDI(g,c1,F) + LDI(be,c1,F);
    xr[c0]=xv0; xr[c1]=xv1;
    size_t ob = ((size_t)(r/NN)*2)*NN*DD + (size_t)(r%NN)*DD;
    out[ob+c0] = xv0;
    out[ob+c1] = xv1;
    __syncthreads();
    float s0=0,s1=0,o0=0,o1=0;
    for(int k=0;k<DD;k++){
        float v=xr[k];
        s0+=v*LDI(subj_w,(size_t)k*DD+c0,F); s1+=v*LDI(subj_w,(size_t)k*DD+c1,F);
        o0+=v*LDI(obj_w,(size_t)k*DD+c0,F);  o1+=v*LDI(obj_w,(size_t)k*DD+c1,F);
    }
    float* xsl=a; float* xol=a+DD;
    xsl[c0]=fmaxf(s0+LDI(subj_b,c0,F),0.f)*m;
    xsl[c1]=fmaxf(s1+LDI(subj_b,c1,F),0.f)*m;
    xol[c0]=fmaxf(o0+LDI(obj_b,c0,F),0.f)*m;
    xol[c1]=fmaxf(o1+LDI(obj_b,c1,F),0.f)*m;
    __syncthreads();
    float ps_=0.f, po_=0.f;
    for(int k=t;k<DD;k+=256){ ps_+=xsl[k]*LDI(rs_w,k,F); po_+=xol[k]*LDI(rs_w,k,F); }
    red[t]=ps_; __syncthreads();
    for(int o=128;o>0;o>>=1){ if(t<o) red[t]+=red[t+o]; __syncthreads(); }
    if(t==0) *sc(out,S_SS+r)=red[0];
    __syncthreads();
    red[t]=po_; __syncthreads();
    for(int o=128;o>0;o>>=1){ if(t<o) red[t]+=red[t+o]; __syncthreads(); }
    if(t==0) *sc(out,S_SO+r)=red[0];
    if(t<FF){
        float acc=0.f;
        for(int k=0;k<DD;k++) acc+=xsl[k]*LDI(rf_w,(size_t)k*FF+t,F);
        *sc(out,S_FS+r*FF+t)=acc;
    } else if(t>=128 && t<128+FF){
        int f=t-128;
        float acc=0.f;
        for(int k=0;k<DD;k++) acc+=xol[k]*LDI(rf_w,(size_t)k*FF+f,F);
        *sc(out,S_FO+r*FF+f)=acc;
    }
}

// ---------------- K2: pos_self -> scratch (f32) ----------------
__global__ void k_pos_self(const bf16* __restrict__ images, const bf16* __restrict__ sb,
                           const bf16* __restrict__ w1, const bf16* __restrict__ b1,
                           const bf16* __restrict__ g, const bf16* __restrict__ be,
                           const bf16* __restrict__ w2, const bf16* __restrict__ b2,
                           float* out){
    __shared__ float h[PD];
    __shared__ float stat[2];
    __shared__ int fm;
    int r=blockIdx.x, t=threadIdx.x;
    if(t==0) fm=detect_f32(images);
    __syncthreads();
    int F=fm;
    float acc=0.f;
    for(int q=0;q<8;q++) acc+=LDI(sb,(size_t)r*8+q,F)*LDI(w1,(size_t)q*PD+t,F);
    acc=fmaxf(acc+LDI(b1,t,F),0.f);
    h[t]=acc; __syncthreads();
    if(t==0){
        float sm=0; for(int k=0;k<PD;k++) sm+=h[k];
        float mean=sm/PD;
        float v=0; for(int k=0;k<PD;k++){float d=h[k]-mean; v+=d*d;}
        stat[0]=mean; stat[1]=rsqrtf(v/PD+1e-5f);
    }
    __syncthreads();
    float hn=(acc-stat[0])*stat[1]*LDI(g,t,F)+LDI(be,t,F);
    h[t]=hn; __syncthreads();
    float acc2=0;
    for(int k=0;k<PD;k++) acc2+=h[k]*LDI(w2,(size_t)k*PD+t,F);
    float mi=*sc(out,S_MF+r);
    *sc(out,S_PS+r*PD+t)=fmaxf(acc2+LDI(b2,t,F),0.f)*mi;
}

// ---------------- K3: fused pair loop; writes Ahat bits + rl into slab b ----------------
__global__ void k_row(const bf16* __restrict__ images, const bf16* __restrict__ bbox,
                      const bf16* __restrict__ w1, const bf16* __restrict__ b1,
                      const bf16* __restrict__ g, const bf16* __restrict__ be,
                      const bf16* __restrict__ w2, const bf16* __restrict__ b2,
                      const bf16* __restrict__ rsw, const bf16* __restrict__ rsb,
                      const bf16* __restrict__ rfw, const bf16* __restrict__ rfb,
                      float* out){
    __shared__ float pr_[PD];
    __shared__ float h[PD];
    __shared__ float red[128];
    __shared__ float stat[6];
    __shared__ int fm;
    int r=blockIdx.x, t=threadIdx.x;
    int b=r/NN, i=r%NN;
    if(t==0) fm=detect_f32(images);
    __syncthreads();
    int F=fm;
    float* o1b = out + (size_t)(2*b+1)*NN*DD;
    float mi=*sc(out,S_MF+r);
    float rsbv=LDI(rsb,0,F);
    if(t==0){ stat[2]=-1e30f; stat[3]=0.f; }
    float accv=0.f;
    __syncthreads();
    for(int j=0;j<NN;j++){
        float mj=*sc(out,S_MF+b*NN+j);
        if(j==i){
            if(t<PD) pr_[t]=*sc(out,S_PS+r*PD+t);
        } else {
            size_t bbase=((size_t)r*NN+j)*8;
            if(t<PD){
                float a=0.f;
                for(int q=0;q<8;q++) a+=LDI(bbox,bbase+q,F)*LDI(w1,(size_t)q*PD+t,F);
                h[t]=fmaxf(a+LDI(b1,t,F),0.f);
            }
            __syncthreads();
            if(t==0){
                float sm=0; for(int k=0;k<PD;k++) sm+=h[k];
                float mean=sm/PD;
                float v=0; for(int k=0;k<PD;k++){float d=h[k]-mean; v+=d*d;}
                stat[0]=mean; stat[1]=rsqrtf(v/PD+1e-5f);
            }
            __syncthreads();
            if(t<PD) pr_[t]=(h[t]-stat[0])*stat[1]*LDI(g,t,F)+LDI(be,t,F);
            __syncthreads();
            if(t<PD){
                float a=0.f;
                for(int k=0;k<PD;k++) a+=pr_[k]*LDI(w2,(size_t)k*PD+t,F);
                h[t]=fmaxf(a+LDI(b2,t,F),0.f)*mi*mj;
            }
            __syncthreads();
            if(t<PD) pr_[t]=h[t];
        }
        __syncthreads();
        red[t]=(t<PD)? pr_[t]*LDI(rsw,DD+t,F) : 0.f;
        __syncthreads();
        for(int o=64;o>0;o>>=1){ if(t<o) red[t]+=red[t+o]; __syncthreads(); }
        if(t==0){
            float base=(j==i)? *sc(out,S_SS+r) : *sc(out,S_SO+b*NN+j);
            float lgj=mi*base + red[0] + rsbv;
            bool af=(j==i) || (lgj>0.f && mi>0.5f && mj>0.5f);
            o1b[i*NN+j]=af?1.f:0.f;                      // Ahat bit
            float lgm=(mi>0.5f && mj>0.5f)? lgj : -1e9f;
            float mnew=fmaxf(stat[2],lgm);
            float scl=expf(stat[2]-mnew);
            float wj=expf(lgm-mnew);
            stat[3]=stat[3]*scl+wj; stat[2]=mnew; stat[4]=scl; stat[5]=wj;
        }
        __syncthreads();
        if(t<FF){
            float fp=0.f;
            for(int k=0;k<PD;k++) fp+=pr_[k]*LDI(rfw,(size_t)(DD+k)*FF+t,F);
            float fb=(j==i)? *sc(out,S_FS+r*FF+t) : *sc(out,S_FO+(b*NN+j)*FF+t);
            float fd=fmaxf(mi*fb+fp+LDI(rfb,t,F),0.f);
            accv=accv*stat[4]+stat[5]*fd;
        }
        __syncthreads();
    }
    if(t<FF) o1b[2500 + i*FF + t]=accv/stat[3]*mi;       // rl
}

// ---------------- K4: normalized adjacency from slab Ahat bits -> ws An ----------------
__global__ void k_adj(const float* __restrict__ out, float* __restrict__ An){
    __shared__ float Af[NN*NN];
    __shared__ float dinv[NN];
    int b=blockIdx.x, t=threadIdx.x;
    const float* o1b = out + (size_t)(2*b+1)*NN*DD;
    for(int idx=t; idx<NN*NN; idx+=256) Af[idx]=(o1b[idx]>0.5f)?1.f:0.f;
    __syncthreads();
    if(t<NN){
        float dg=0.f;
        for(int i=0;i<NN;i++) dg+=Af[i*NN+t];
        dinv[t]=rsqrtf(dg);
    }
    __syncthreads();
    for(int idx=t; idx<NN*NN; idx+=256){
        int i=idx/NN, j=idx%NN;
        An[(size_t)b*NN*NN+idx]=Af[idx]*dinv[i]*dinv[j];
    }
}

// ---------------- KT: T = X @ W  (10-row x 256-col register tiles) ----------------
// mode 0: X = [out_ch0 | slab_rl], K=592, NCOL=592
// mode 1: X = x1 (ws),             K=592, NCOL=512
// mode 2: X = x2 (ws),             K=512, NCOL=512
__global__ void kt(int mode, const bf16* __restrict__ images, const float* __restrict__ out,
                   const float* __restrict__ Xws, const bf16* __restrict__ W,
                   float* __restrict__ T, int K, int NCOL, int NTILE){
    __shared__ float xs[10*GG];    // 23,680 B max
    __shared__ int fm;
    int blk=blockIdx.x, t=threadIdx.x;
    int rg=blk/NTILE, tile=blk%NTILE;
    if(t==0) fm=detect_f32(images);
    // stage 10 rows
    for(int idx=t; idx<10*K; idx+=256){
        int row=idx/K, k=idx-row*K;
        int gr=rg*10+row;
        float v;
        if(mode==0){
            int b=gr/NN, i=gr-b*NN;
            if(k<DD) v=out[(size_t)(2*b)*NN*DD + (size_t)i*DD + k];
            else     v=out[(size_t)(2*b+1)*NN*DD + 2500 + i*FF + (k-DD)];
        } else {
            v=Xws[(size_t)gr*K+k];
        }
        xs[row*K+k]=v;
    }
    __syncthreads();
    int F=fm;
    int c=tile*256+t;
    if(c>=NCOL) return;
    float acc[10];
    #pragma unroll
    for(int u=0;u<10;u++) acc[u]=0.f;
    for(int k=0;k<K;k++){
        float w=LDI(W,(size_t)k*NCOL+c,F);
        #pragma unroll
        for(int u=0;u<10;u++) acc[u]+=xs[u*K+k]*w;
    }
    int gr0=rg*10;
    #pragma unroll
    for(int u=0;u<10;u++) T[(size_t)(gr0+u)*NCOL+c]=acc[u];
}

// ---------------- KA: aggregation x_out[b,j,:] = relu(Σ_i An[b,i,j] T[b,i,:] + bias) ----------------
// mode 0 -> x1 ws (NCOL=592); mode 1 -> x2 ws (NCOL=512); mode 2 -> out ch1 (NCOL=512)
__global__ void ka(int mode, const bf16* __restrict__ images, const float* __restrict__ An,
                   const float* __restrict__ T, const bf16* __restrict__ bias,
                   float* __restrict__ Xout, float* __restrict__ out, int NCOL){
    __shared__ float acol[NN];
    __shared__ int fm;
    int rj=blockIdx.x, t=threadIdx.x;
    int b=rj/NN, j=rj-b*NN;
    if(t==0) fm=detect_f32(images);
    if(t<NN) acol[t]=An[(size_t)b*NN*NN + t*NN + j];
    __syncthreads();
    int F=fm;
    const float* Tb = T + (size_t)b*NN*NCOL;
    for(int c=t;c<NCOL;c+=256){
        float acc=0.f;
        for(int i=0;i<NN;i++) acc+=acol[i]*Tb[(size_t)i*NCOL+c];
        float v=fmaxf(acc+LDI(bias,c,F),0.f);
        if(mode==2) out[(size_t)(2*b+1)*NN*DD + (size_t)j*DD + c]=v;
        else        Xout[(size_t)rj*NCOL+c]=v;
    }
}

extern "C" void kernel_launch(void* const* d_in, const int* in_sizes, int n_in,
                              void* d_out, int out_size, void* d_ws, size_t ws_size,
                              hipStream_t stream) {
    const bf16* images  = (const bf16*)d_in[0];
    const bf16* selfbbox= (const bf16*)d_in[1];
    const bf16* bbox    = (const bf16*)d_in[2];
    const bf16* pre_w   = (const bf16*)d_in[3];
    const bf16* pre_b   = (const bf16*)d_in[4];
    const bf16* pre_g   = (const bf16*)d_in[5];
    const bf16* pre_be  = (const bf16*)d_in[6];
    const bf16* subj_w  = (const bf16*)d_in[7];
    const bf16* subj_b  = (const bf16*)d_in[8];
    const bf16* obj_w   = (const bf16*)d_in[9];
    const bf16* obj_b   = (const bf16*)d_in[10];
    const bf16* ps1_w   = (const bf16*)d_in[11];
    const bf16* ps1_b   = (const bf16*)d_in[12];
    const bf16* ps_g    = (const bf16*)d_in[13];
    const bf16* ps_be   = (const bf16*)d_in[14];
    const bf16* ps2_w   = (const bf16*)d_in[15];
    const bf16* ps2_b   = (const bf16*)d_in[16];
    const bf16* pr1_w   = (const bf16*)d_in[17];
    const bf16* pr1_b   = (const bf16*)d_in[18];
    const bf16* pr_g    = (const bf16*)d_in[19];
    const bf16* pr_be   = (const bf16*)d_in[20];
    const bf16* pr2_w   = (const bf16*)d_in[21];
    const bf16* pr2_b   = (const bf16*)d_in[22];
    const bf16* rs_w    = (const bf16*)d_in[23];
    const bf16* rs_b    = (const bf16*)d_in[24];
    const bf16* rf_w    = (const bf16*)d_in[25];
    const bf16* rf_b    = (const bf16*)d_in[26];
    const bf16* g1_w    = (const bf16*)d_in[27];
    const bf16* g1_b    = (const bf16*)d_in[28];
    const bf16* g2_w    = (const bf16*)d_in[29];
    const bf16* g2_b    = (const bf16*)d_in[30];
    const bf16* g3_w    = (const bf16*)d_in[31];
    const bf16* g3_b    = (const bf16*)d_in[32];

    float* out = (float*)d_out;   // f32 output
    float* ws  = (float*)d_ws;
    float* An  = ws + 0;          // 80,000
    float* T   = ws + 80000;      // 947,200
    float* x1  = ws + 1027200;    // 947,200
    float* x2  = ws + 1974400;    // 819,200  (end 2,793,600 f32 = 11.2 MB)

    k_pre<<<BN, 256, 0, stream>>>(images, pre_w, pre_b, pre_g, pre_be,
                                  subj_w, subj_b, obj_w, obj_b, rs_w, rf_w, out);
    k_pos_self<<<BN, PD, 0, stream>>>(images, selfbbox, ps1_w, ps1_b, ps_g, ps_be,
                                      ps2_w, ps2_b, out);
    k_row<<<BN, 128, 0, stream>>>(images, bbox, pr1_w, pr1_b, pr_g, pr_be, pr2_w, pr2_b,
                                  rs_w, rs_b, rf_w, rf_b, out);
    k_adj<<<BB, 256, 0, stream>>>(out, An);

    kt<<<160*3, 256, 0, stream>>>(0, images, out, x1, g1_w, T, GG, GG, 3);
    ka<<<BN, 256, 0, stream>>>(0, images, An, T, g1_b, x1, out, GG);
    kt<<<160*2, 256, 0, stream>>>(1, images, out, x1, g2_w, T, GG, DD, 2);
    ka<<<BN, 256, 0, stream>>>(1, images, An, T, g2_b, x2, out, DD);
    kt<<<160*2, 256, 0, stream>>>(2, images, out, x2, g3_w, T, DD, DD, 2);
    ka<<<BN, 256, 0, stream>>>(2, images, An, T, g3_b, x2, out, DD);
}

// Round 15
// 1205.632 us; speedup vs baseline: 9.9474x; 1.3300x over previous
//
#include <hip/hip_runtime.h>
#include <hip/hip_bf16.h>

typedef __hip_bfloat16 bf16;

#define BB 32
#define NN 50
#define DIN 2048
#define DD 512
#define PD 64
#define FF 80
#define GG 592
#define BN (BB*NN)      // 1600

// ---------------- ws layout (f32 words) ----------------
#define O_FLAG  0
#define O_MF    16
#define O_SS    1616
#define O_SO    3216
#define O_PS    4816
#define O_FS    107216
#define O_FO    235216
#define O_RL    363216
#define O_AH    491216
#define O_AN    571216
#define O_T     651216
#define O_X1    1598416
#define O_X2    2545616
#define O_WPRE  3364816
#define O_BPRE  4413392
#define O_GPRE  4413904
#define O_EPRE  4414416
#define O_WSUBJ 4414928
#define O_BSUBJ 4677072
#define O_WOBJ  4677584
#define O_BOBJ  4939728
#define O_WPS1  4940240
#define O_BPS1  4940752
#define O_GPS   4940816
#define O_EPS   4940880
#define O_WPS2  4940944
#define O_BPS2  4945040
#define O_WPR1  4945104
#define O_BPR1  4945616
#define O_GPR   4945680
#define O_EPR   4945744
#define O_WPR2  4945808
#define O_BPR2  4949904
#define O_WRS   4949968
#define O_BRS   4950544
#define O_WRF   4950560
#define O_BRF   4996640
#define O_WG1   4996736
#define O_BG1   5347200
#define O_WG2   5347792
#define O_BG2   5650896
#define O_WG3   5651408
#define O_BG3   5913552
// end 5,914,064 words = 23.7 MB

__device__ __forceinline__ float b2f(bf16 x){ return __bfloat162float(x); }

// Load logical f32 element i of an input buffer (bf16-pair reconstruction when F=1).
__device__ __forceinline__ float LDI(const bf16* p, size_t i, int f32m){
    if(f32m){
        bf16 a=p[2*i], b=p[2*i+1];
        unsigned short lo,hi;
        __builtin_memcpy(&lo,&a,2); __builtin_memcpy(&hi,&b,2);
        unsigned v=((unsigned)hi<<16)|(unsigned)lo;
        float f; __builtin_memcpy(&f,&v,4);
        return f;
    }
    return __bfloat162float(p[i]);
}

// ---------------- flag: detect split-f32 vs true-bf16 inputs (once) ----------------
__global__ void k_flag(const bf16* __restrict__ images, float* __restrict__ ws){
    __shared__ int cnt;
    if(threadIdx.x==0) cnt=0;
    __syncthreads();
    bf16 h=images[2*threadIdx.x];
    unsigned short u; __builtin_memcpy(&u,&h,2);
    unsigned e=(u>>7)&0xFF;
    int sane=((u&0x7FFF)==0 || (e>=0x70&&e<=0x85))?1:0;
    atomicAdd(&cnt,sane);
    __syncthreads();
    if(threadIdx.x==0) ws[O_FLAG]=(cnt<48)?1.f:0.f;
}

// ---------------- kw: convert all weights to f32 in ws ----------------
__device__ __forceinline__ void conv(const bf16* s, float* d, int n, int F, int i0, int st){
    for(int g=i0; g<n; g+=st) d[g]=LDI(s,(size_t)g,F);
}
__global__ void kw(const bf16* p0,const bf16* p1,const bf16* p2,const bf16* p3,
                   const bf16* p4,const bf16* p5,const bf16* p6,const bf16* p7,
                   const bf16* p8,const bf16* p9,const bf16* p10,const bf16* p11,
                   const bf16* p12,const bf16* p13,const bf16* p14,const bf16* p15,
                   const bf16* p16,const bf16* p17,const bf16* p18,const bf16* p19,
                   const bf16* p20,const bf16* p21,const bf16* p22,const bf16* p23,
                   const bf16* p24,const bf16* p25,const bf16* p26,const bf16* p27,
                   const bf16* p28,const bf16* p29, float* __restrict__ ws){
    int F=ws[O_FLAG]>0.5f;
    int i0=blockIdx.x*256+threadIdx.x, st=gridDim.x*256;
    conv(p0, ws+O_WPRE, 1048576,F,i0,st);
    conv(p1, ws+O_BPRE, 512,F,i0,st);
    conv(p2, ws+O_GPRE, 512,F,i0,st);
    conv(p3, ws+O_EPRE, 512,F,i0,st);
    conv(p4, ws+O_WSUBJ,262144,F,i0,st);
    conv(p5, ws+O_BSUBJ,512,F,i0,st);
    conv(p6, ws+O_WOBJ, 262144,F,i0,st);
    conv(p7, ws+O_BOBJ, 512,F,i0,st);
    conv(p8, ws+O_WPS1, 512,F,i0,st);
    conv(p9, ws+O_BPS1, 64,F,i0,st);
    conv(p10,ws+O_GPS,  64,F,i0,st);
    conv(p11,ws+O_EPS,  64,F,i0,st);
    conv(p12,ws+O_WPS2, 4096,F,i0,st);
    conv(p13,ws+O_BPS2, 64,F,i0,st);
    conv(p14,ws+O_WPR1, 512,F,i0,st);
    conv(p15,ws+O_BPR1, 64,F,i0,st);
    conv(p16,ws+O_GPR,  64,F,i0,st);
    conv(p17,ws+O_EPR,  64,F,i0,st);
    conv(p18,ws+O_WPR2, 4096,F,i0,st);
    conv(p19,ws+O_BPR2, 64,F,i0,st);
    conv(p20,ws+O_WRS,  576,F,i0,st);
    conv(p21,ws+O_BRS,  1,F,i0,st);
    conv(p22,ws+O_WRF,  46080,F,i0,st);
    conv(p23,ws+O_BRF,  80,F,i0,st);
    conv(p24,ws+O_WG1,  350464,F,i0,st);
    conv(p25,ws+O_BG1,  592,F,i0,st);
    conv(p26,ws+O_WG2,  303104,F,i0,st);
    conv(p27,ws+O_BG2,  512,F,i0,st);
    conv(p28,ws+O_WG3,  262144,F,i0,st);
    conv(p29,ws+O_BG3,  512,F,i0,st);
}

// ---------------- k_pre: 2 rows/block; mask, LN-pre, subj/obj projections ----------------
__global__ void k_pre(const bf16* __restrict__ images, float* __restrict__ ws,
                      float* __restrict__ out){
    __shared__ float a[2*DIN];
    __shared__ float xr[2*DD];
    __shared__ float red[256];
    int blk=blockIdx.x, t=threadIdx.x;
    int r0=blk*2;
    int F=ws[O_FLAG]>0.5f;
    const float* wPre=ws+O_WPRE; const float* bPre=ws+O_BPRE;
    const float* gPre=ws+O_GPRE; const float* ePre=ws+O_EPRE;
    const float* wSu=ws+O_WSUBJ; const float* bSu=ws+O_BSUBJ;
    const float* wOb=ws+O_WOBJ;  const float* bOb=ws+O_BOBJ;
    const float* wRs=ws+O_WRS;   const float* wRf=ws+O_WRF;

    float s0=0.f,s1=0.f;
    for(int idx=t; idx<2*DIN; idx+=256){
        float v=LDI(images,(size_t)r0*DIN+idx,F);
        a[idx]=v;
        if(idx<DIN) s0+=v; else s1+=v;
    }
    red[t]=s0; __syncthreads();
    for(int o=128;o>0;o>>=1){ if(t<o) red[t]+=red[t+o]; __syncthreads(); }
    float m0=(red[0]!=0.f)?1.f:0.f;
    __syncthreads();
    red[t]=s1; __syncthreads();
    for(int o=128;o>0;o>>=1){ if(t<o) red[t]+=red[t+o]; __syncthreads(); }
    float m1=(red[0]!=0.f)?1.f:0.f;
    if(t==0){
        ws[O_MF+r0]=m0; ws[O_MF+r0+1]=m1;
        out[(size_t)BB*2*NN*DD+r0]=1.f-m0;
        out[(size_t)BB*2*NN*DD+r0+1]=1.f-m1;
    }
    __syncthreads();
    int c0=t, c1=t+256;
    float a00=0,a01=0,a10=0,a11=0;
    for(int k=0;k<DIN;k++){
        float w0=wPre[(size_t)k*DD+c0];
        float w1v=wPre[(size_t)k*DD+c1];
        float v0=a[k], v1=a[DIN+k];
        a00+=v0*w0; a01+=v0*w1v; a10+=v1*w0; a11+=v1*w1v;
    }
    float y00=fmaxf(a00+bPre[c0],0.f), y01=fmaxf(a01+bPre[c1],0.f);
    float y10=fmaxf(a10+bPre[c0],0.f), y11=fmaxf(a11+bPre[c1],0.f);
    // LN row 0
    __syncthreads();
    red[t]=y00+y01; __syncthreads();
    for(int o=128;o>0;o>>=1){ if(t<o) red[t]+=red[t+o]; __syncthreads(); }
    float mean0=red[0]/DD;
    __syncthreads();
    float d00=y00-mean0, d01=y01-mean0;
    red[t]=d00*d00+d01*d01; __syncthreads();
    for(int o=128;o>0;o>>=1){ if(t<o) red[t]+=red[t+o]; __syncthreads(); }
    float rstd0=rsqrtf(red[0]/DD+1e-5f);
    float xv00=d00*rstd0*gPre[c0]+ePre[c0];
    float xv01=d01*rstd0*gPre[c1]+ePre[c1];
    xr[c0]=xv00; xr[c1]=xv01;
    {
        size_t ob=((size_t)(r0/NN)*2)*NN*DD+(size_t)(r0%NN)*DD;
        out[ob+c0]=xv00; out[ob+c1]=xv01;
    }
    // LN row 1
    __syncthreads();
    red[t]=y10+y11; __syncthreads();
    for(int o=128;o>0;o>>=1){ if(t<o) red[t]+=red[t+o]; __syncthreads(); }
    float mean1=red[0]/DD;
    __syncthreads();
    float d10=y10-mean1, d11=y11-mean1;
    red[t]=d10*d10+d11*d11; __syncthreads();
    for(int o=128;o>0;o>>=1){ if(t<o) red[t]+=red[t+o]; __syncthreads(); }
    float rstd1=rsqrtf(red[0]/DD+1e-5f);
    float xv10=d10*rstd1*gPre[c0]+ePre[c0];
    float xv11=d11*rstd1*gPre[c1]+ePre[c1];
    xr[DD+c0]=xv10; xr[DD+c1]=xv11;
    {
        int r1=r0+1;
        size_t ob=((size_t)(r1/NN)*2)*NN*DD+(size_t)(r1%NN)*DD;
        out[ob+c0]=xv10; out[ob+c1]=xv11;
    }
    __syncthreads();
    // subj/obj GEMM (2 rows)
    float su00=0,su01=0,su10=0,su11=0, oo00=0,oo01=0,oo10=0,oo11=0;
    for(int k=0;k<DD;k++){
        float ws0=wSu[(size_t)k*DD+c0], ws1=wSu[(size_t)k*DD+c1];
        float wo0=wOb[(size_t)k*DD+c0], wo1=wOb[(size_t)k*DD+c1];
        float v0=xr[k], v1=xr[DD+k];
        su00+=v0*ws0; su01+=v0*ws1; su10+=v1*ws0; su11+=v1*ws1;
        oo00+=v0*wo0; oo01+=v0*wo1; oo10+=v1*wo0; oo11+=v1*wo1;
    }
    __syncthreads();   // a[] image data no longer needed
    a[c0]     =fmaxf(su00+bSu[c0],0.f)*m0;   // xs r0
    a[c1]     =fmaxf(su01+bSu[c1],0.f)*m0;
    a[DD+c0]  =fmaxf(su10+bSu[c0],0.f)*m1;   // xs r1
    a[DD+c1]  =fmaxf(su11+bSu[c1],0.f)*m1;
    a[2*DD+c0]=fmaxf(oo00+bOb[c0],0.f)*m0;   // xo r0
    a[2*DD+c1]=fmaxf(oo01+bOb[c1],0.f)*m0;
    a[3*DD+c0]=fmaxf(oo10+bOb[c0],0.f)*m1;   // xo r1
    a[3*DD+c1]=fmaxf(oo11+bOb[c1],0.f)*m1;
    __syncthreads();
    for(int row=0;row<2;row++){
        float ps=0.f,po=0.f;
        for(int k=t;k<DD;k+=256){ ps+=a[row*DD+k]*wRs[k]; po+=a[2*DD+row*DD+k]*wRs[k]; }
        red[t]=ps; __syncthreads();
        for(int o=128;o>0;o>>=1){ if(t<o) red[t]+=red[t+o]; __syncthreads(); }
        if(t==0) ws[O_SS+r0+row]=red[0];
        __syncthreads();
        red[t]=po; __syncthreads();
        for(int o=128;o>0;o>>=1){ if(t<o) red[t]+=red[t+o]; __syncthreads(); }
        if(t==0) ws[O_SO+r0+row]=red[0];
        __syncthreads();
    }
    if(t<240){
        int grp=t/80, f=t-grp*80;
        const float* xv=(grp==0)? a : (grp==1)? a+DD : a+2*DD;
        float acc=0.f;
        for(int k=0;k<DD;k++) acc+=xv[k]*wRf[(size_t)k*FF+f];
        if(grp<2) ws[O_FS+(size_t)(r0+grp)*FF+f]=acc;
        else      ws[O_FO+(size_t)r0*FF+f]=acc;
    }
    if(t<FF){
        float acc=0.f;
        for(int k=0;k<DD;k++) acc+=a[3*DD+k]*wRf[(size_t)k*FF+t];
        ws[O_FO+(size_t)(r0+1)*FF+t]=acc;
    }
}

// ---------------- k_pos_self ----------------
__global__ void k_pos_self(const bf16* __restrict__ sb, float* __restrict__ ws){
    __shared__ float h[PD];
    __shared__ float stat[2];
    int r=blockIdx.x, t=threadIdx.x;
    int F=ws[O_FLAG]>0.5f;
    const float* w1=ws+O_WPS1;
    float acc=0.f;
    for(int q=0;q<8;q++) acc+=LDI(sb,(size_t)r*8+q,F)*w1[q*PD+t];
    acc=fmaxf(acc+ws[O_BPS1+t],0.f);
    h[t]=acc; __syncthreads();
    if(t==0){
        float sm=0; for(int k=0;k<PD;k++) sm+=h[k];
        float mean=sm/PD;
        float v=0; for(int k=0;k<PD;k++){float d=h[k]-mean; v+=d*d;}
        stat[0]=mean; stat[1]=rsqrtf(v/PD+1e-5f);
    }
    __syncthreads();
    float hn=(acc-stat[0])*stat[1]*ws[O_GPS+t]+ws[O_EPS+t];
    h[t]=hn; __syncthreads();
    float a2=0.f;
    const float* w2=ws+O_WPS2;
    for(int k=0;k<PD;k++) a2+=h[k]*w2[k*PD+t];
    ws[O_PS+(size_t)r*PD+t]=fmaxf(a2+ws[O_BPS2+t],0.f)*ws[O_MF+r];
}

// ---------------- k_row: fused pair loop, weights staged in LDS ----------------
#define LW1 0
#define LB1 512
#define LG_ 576
#define LBE 640
#define LW2 704
#define LB2 4800
#define LRST 4864
#define LRFB 4928
#define LRFT 5008
#define LTOT 10128

__global__ void k_row(const bf16* __restrict__ bbox, float* __restrict__ ws){
    __shared__ float L[LTOT];
    __shared__ float pr_[PD];
    __shared__ float h[PD];
    __shared__ float red[128];
    __shared__ float stat[6];
    int r=blockIdx.x, t=threadIdx.x;
    int b=r/NN, i=r%NN;
    int F=ws[O_FLAG]>0.5f;
    for(int idx=t; idx<LTOT; idx+=128){
        float v;
        if(idx<LB1)       v=ws[O_WPR1+idx];
        else if(idx<LG_)  v=ws[O_BPR1+idx-LB1];
        else if(idx<LBE)  v=ws[O_GPR+idx-LG_];
        else if(idx<LW2)  v=ws[O_EPR+idx-LBE];
        else if(idx<LB2)  v=ws[O_WPR2+idx-LW2];
        else if(idx<LRST) v=ws[O_BPR2+idx-LB2];
        else if(idx<LRFB) v=ws[O_WRS+512+idx-LRST];
        else if(idx<LRFT) v=ws[O_BRF+idx-LRFB];
        else              v=ws[O_WRF+512*FF+idx-LRFT];
        L[idx]=v;
    }
    float mi=ws[O_MF+r];
    float rsbv=ws[O_BRS];
    if(t==0){ stat[2]=-1e30f; stat[3]=0.f; }
    float accv=0.f;
    __syncthreads();
    for(int j=0;j<NN;j++){
        float mj=ws[O_MF+b*NN+j];
        if(j==i){
            if(t<PD) pr_[t]=ws[O_PS+(size_t)r*PD+t];
        } else {
            size_t bbase=((size_t)r*NN+j)*8;
            if(t<PD){
                float a=0.f;
                for(int q=0;q<8;q++) a+=LDI(bbox,bbase+q,F)*L[LW1+q*PD+t];
                h[t]=fmaxf(a+L[LB1+t],0.f);
            }
            __syncthreads();
            if(t==0){
                float sm=0; for(int k=0;k<PD;k++) sm+=h[k];
                float mean=sm/PD;
                float v=0; for(int k=0;k<PD;k++){float d=h[k]-mean; v+=d*d;}
                stat[0]=mean; stat[1]=rsqrtf(v/PD+1e-5f);
            }
            __syncthreads();
            if(t<PD) pr_[t]=(h[t]-stat[0])*stat[1]*L[LG_+t]+L[LBE+t];
            __syncthreads();
            if(t<PD){
                float a=0.f;
                for(int k=0;k<PD;k++) a+=pr_[k]*L[LW2+k*PD+t];
                h[t]=fmaxf(a+L[LB2+t],0.f)*mi*mj;
            }
            __syncthreads();
            if(t<PD) pr_[t]=h[t];
        }
        __syncthreads();
        red[t]=(t<PD)? pr_[t]*L[LRST+t] : 0.f;
        __syncthreads();
        for(int o=64;o>0;o>>=1){ if(t<o) red[t]+=red[t+o]; __syncthreads(); }
        if(t==0){
            float base=(j==i)? ws[O_SS+r] : ws[O_SO+b*NN+j];
            float lgj=mi*base+red[0]+rsbv;
            bool af=(j==i) || (lgj>0.f && mi>0.5f && mj>0.5f);
            ws[O_AH+(size_t)r*NN+j]=af?1.f:0.f;
            float lgm=(mi>0.5f && mj>0.5f)? lgj : -1e9f;
            float mnew=fmaxf(stat[2],lgm);
            float scl=expf(stat[2]-mnew);
            float wj=expf(lgm-mnew);
            stat[3]=stat[3]*scl+wj; stat[2]=mnew; stat[4]=scl; stat[5]=wj;
        }
        __syncthreads();
        if(t<FF){
            float fp=0.f;
            for(int k=0;k<PD;k++) fp+=pr_[k]*L[LRFT+k*FF+t];
            float fb=(j==i)? ws[O_FS+(size_t)r*FF+t] : ws[O_FO+(size_t)(b*NN+j)*FF+t];
            float fd=fmaxf(mi*fb+fp+L[LRFB+t],0.f);
            accv=accv*stat[4]+stat[5]*fd;
        }
        __syncthreads();
    }
    if(t<FF) ws[O_RL+(size_t)r*FF+t]=accv/stat[3]*mi;
}

// ---------------- k_adj ----------------
__global__ void k_adj(float* __restrict__ ws){
    __shared__ float Af[NN*NN];
    __shared__ float dinv[NN];
    int b=blockIdx.x, t=threadIdx.x;
    for(int idx=t; idx<NN*NN; idx+=256) Af[idx]=(ws[O_AH+(size_t)b*NN*NN+idx]>0.5f)?1.f:0.f;
    __syncthreads();
    if(t<NN){
        float dg=0.f;
        for(int i=0;i<NN;i++) dg+=Af[i*NN+t];
        dinv[t]=rsqrtf(dg);
    }
    __syncthreads();
    for(int idx=t; idx<NN*NN; idx+=256){
        int i=idx/NN, j=idx%NN;
        ws[O_AN+(size_t)b*NN*NN+idx]=Af[idx]*dinv[i]*dinv[j];
    }
}

// ---------------- kt: T = X @ W (10-row x 256-col register tiles) ----------------
__global__ void kt(int mode, const float* __restrict__ out, const float* __restrict__ ws,
                   const float* __restrict__ W, float* __restrict__ T,
                   int K, int NCOL, int NTILE){
    __shared__ float xs[10*GG];
    int blk=blockIdx.x, t=threadIdx.x;
    int rg=blk/NTILE, tile=blk%NTILE;
    for(int idx=t; idx<10*K; idx+=256){
        int row=idx/K, k=idx-row*K;
        int gr=rg*10+row;
        float v;
        if(mode==0){
            int bb=gr/NN, ii=gr-bb*NN;
            if(k<DD) v=out[(size_t)(2*bb)*NN*DD+(size_t)ii*DD+k];
            else     v=ws[O_RL+(size_t)gr*FF+(k-DD)];
        } else if(mode==1) v=ws[O_X1+(size_t)gr*GG+k];
        else               v=ws[O_X2+(size_t)gr*DD+k];
        xs[row*K+k]=v;
    }
    __syncthreads();
    int c=tile*256+t;
    if(c>=NCOL) return;
    float acc[10];
    #pragma unroll
    for(int u=0;u<10;u++) acc[u]=0.f;
    for(int k=0;k<K;k++){
        float w=W[(size_t)k*NCOL+c];
        #pragma unroll
        for(int u=0;u<10;u++) acc[u]+=xs[u*K+k]*w;
    }
    int gr0=rg*10;
    #pragma unroll
    for(int u=0;u<10;u++) T[(size_t)(gr0+u)*NCOL+c]=acc[u];
}

// ---------------- ka: aggregation ----------------
__global__ void ka(int mode, float* __restrict__ ws, const float* __restrict__ bias,
                   float* __restrict__ out, int NCOL){
    __shared__ float acol[NN];
    int rj=blockIdx.x, t=threadIdx.x;
    int b=rj/NN, j=rj-b*NN;
    if(t<NN) acol[t]=ws[O_AN+(size_t)b*NN*NN+t*NN+j];
    __syncthreads();
    const float* Tb=ws+O_T+(size_t)b*NN*NCOL;
    for(int c=t;c<NCOL;c+=256){
        float acc=0.f;
        for(int i2=0;i2<NN;i2++) acc+=acol[i2]*Tb[(size_t)i2*NCOL+c];
        float v=fmaxf(acc+bias[c],0.f);
        if(mode==2)      out[(size_t)(2*b+1)*NN*DD+(size_t)j*DD+c]=v;
        else if(mode==1) ws[O_X2+(size_t)rj*DD+c]=v;
        else             ws[O_X1+(size_t)rj*GG+c]=v;
    }
}

extern "C" void kernel_launch(void* const* d_in, const int* in_sizes, int n_in,
                              void* d_out, int out_size, void* d_ws, size_t ws_size,
                              hipStream_t stream) {
    const bf16* images  = (const bf16*)d_in[0];
    const bf16* selfbbox= (const bf16*)d_in[1];
    const bf16* bbox    = (const bf16*)d_in[2];

    float* out=(float*)d_out;
    float* ws =(float*)d_ws;

    k_flag<<<1,64,0,stream>>>(images, ws);
    kw<<<512,256,0,stream>>>((const bf16*)d_in[3],(const bf16*)d_in[4],(const bf16*)d_in[5],
                             (const bf16*)d_in[6],(const bf16*)d_in[7],(const bf16*)d_in[8],
                             (const bf16*)d_in[9],(const bf16*)d_in[10],(const bf16*)d_in[11],
                             (const bf16*)d_in[12],(const bf16*)d_in[13],(const bf16*)d_in[14],
                             (const bf16*)d_in[15],(const bf16*)d_in[16],(const bf16*)d_in[17],
                             (const bf16*)d_in[18],(const bf16*)d_in[19],(const bf16*)d_in[20],
                             (const bf16*)d_in[21],(const bf16*)d_in[22],(const bf16*)d_in[23],
                             (const bf16*)d_in[24],(const bf16*)d_in[25],(const bf16*)d_in[26],
                             (const bf16*)d_in[27],(const bf16*)d_in[28],(const bf16*)d_in[29],
                             (const bf16*)d_in[30],(const bf16*)d_in[31],(const bf16*)d_in[32],
                             ws);
    k_pre<<<BN/2,256,0,stream>>>(images, ws, out);
    k_pos_self<<<BN,PD,0,stream>>>(selfbbox, ws);
    k_row<<<BN,128,0,stream>>>(bbox, ws);
    k_adj<<<BB,256,0,stream>>>(ws);

    kt<<<160*3,256,0,stream>>>(0, out, ws, ws+O_WG1, ws+O_T, GG, GG, 3);
    ka<<<BN,256,0,stream>>>(0, ws, ws+O_BG1, out, GG);
    kt<<<160*2,256,0,stream>>>(1, out, ws, ws+O_WG2, ws+O_T, GG, DD, 2);
    ka<<<BN,256,0,stream>>>(1, ws, ws+O_BG2, out, DD);
    kt<<<160*2,256,0,stream>>>(2, out, ws, ws+O_WG3, ws+O_T, DD, DD, 2);
    ka<<<BN,256,0,stream>>>(2, ws, ws+O_BG3, out, DD);
}